// Round 3
// baseline (28.963 us; speedup 1.0000x reference)
//
#include <hip/hip_runtime.h>

// BoundaryLoss collapses analytically:
//   boundary = min(edt(~mask), edt(mask)) == 0 at EVERY pixel
//   (each pixel is a feature pixel of one of the two sets, where its EDT is 0),
//   so weights == 1.0 exactly and the op is mean(BCE(inputs, targets)).
//
// R3: single-kernel last-block-done reduction (removes the 2nd kernel's
// dispatch latency). Counter in d_ws, zeroed by a hipMemsetAsync graph node.
// Agent-scope atomics for cross-XCD visibility of partials (Guideline 16).

static constexpr int N_TOTAL = 32 * 320 * 320;   // 3,276,800
static constexpr int N4      = N_TOTAL / 4;      // 819,200 float4 elements
static constexpr int THREADS = 256;
static constexpr int BLOCKS  = 800;              // 800*256*4 == N4 exactly
static constexpr int ITERS   = 4;

__global__ __launch_bounds__(THREADS) void bce_loss_kernel(
    const float4* __restrict__ x4, const float4* __restrict__ t4,
    float* __restrict__ partial, unsigned* __restrict__ counter,
    float* __restrict__ out) {
    const int tid    = blockIdx.x * THREADS + threadIdx.x;
    const int stride = BLOCKS * THREADS;

    float acc = 0.0f;
    #pragma unroll
    for (int it = 0; it < ITERS; ++it) {
        const int i = tid + it * stride;
        float4 xv = x4[i];
        float4 tv = t4[i];
        float xs[4] = {xv.x, xv.y, xv.z, xv.w};
        float ts[4] = {tv.x, tv.y, tv.z, tv.w};
        #pragma unroll
        for (int j = 0; j < 4; ++j) {
            float e = __expf(-xs[j]);                       // v_exp_f32
            float p = __builtin_amdgcn_rcpf(1.0f + e);      // v_rcp_f32 (sigmoid)
            acc += -ts[j]         * __logf(p + 1e-6f)
                   - (1.0f - ts[j]) * __logf(1.0f - p + 1e-6f);
        }
    }

    // wave (64-lane) shuffle reduction
    #pragma unroll
    for (int off = 32; off > 0; off >>= 1)
        acc += __shfl_down(acc, off, 64);
    __shared__ float sdata[THREADS / 64];
    __shared__ int s_last;
    const int lane = threadIdx.x & 63;
    const int wave = threadIdx.x >> 6;
    if (lane == 0) sdata[wave] = acc;
    __syncthreads();
    if (threadIdx.x == 0) {
        float s = 0.0f;
        #pragma unroll
        for (int w = 0; w < THREADS / 64; ++w) s += sdata[w];
        // agent-scope store so other XCDs' L2s see it
        __hip_atomic_store(&partial[blockIdx.x], s, __ATOMIC_RELAXED,
                           __HIP_MEMORY_SCOPE_AGENT);
        unsigned old = __hip_atomic_fetch_add(counter, 1u, __ATOMIC_ACQ_REL,
                                              __HIP_MEMORY_SCOPE_AGENT);
        s_last = (old == (unsigned)(BLOCKS - 1));
    }
    __syncthreads();

    if (s_last) {
        // last block: reduce the 800 partials (fixed order -> deterministic)
        float a = 0.0f;
        for (int i = threadIdx.x; i < BLOCKS; i += THREADS)
            a += __hip_atomic_load(&partial[i], __ATOMIC_RELAXED,
                                   __HIP_MEMORY_SCOPE_AGENT);
        #pragma unroll
        for (int off = 32; off > 0; off >>= 1)
            a += __shfl_down(a, off, 64);
        if (lane == 0) sdata[wave] = a;
        __syncthreads();
        if (threadIdx.x == 0) {
            float s = 0.0f;
            #pragma unroll
            for (int w = 0; w < THREADS / 64; ++w) s += sdata[w];
            out[0] = s / (float)N_TOTAL;
        }
    }
}

extern "C" void kernel_launch(void* const* d_in, const int* in_sizes, int n_in,
                              void* d_out, int out_size, void* d_ws, size_t ws_size,
                              hipStream_t stream) {
    const float4* x4 = (const float4*)d_in[0];   // inputs  [32,1,320,320] f32
    const float4* t4 = (const float4*)d_in[1];   // targets [32,1,320,320] f32
    unsigned* counter = (unsigned*)d_ws;                      // 4B counter
    float* partial    = (float*)((char*)d_ws + 256);          // BLOCKS floats
    float* out        = (float*)d_out;                        // scalar f32

    hipMemsetAsync(counter, 0, sizeof(unsigned), stream);
    bce_loss_kernel<<<BLOCKS, THREADS, 0, stream>>>(x4, t4, partial, counter, out);
}

// Round 4
// 11.852 us; speedup vs baseline: 2.4436x; 2.4436x over previous
//
#include <hip/hip_runtime.h>

// BoundaryLoss collapses analytically:
//   boundary = min(edt(~mask), edt(mask)) == 0 at EVERY pixel
//   (each pixel is a feature pixel of one of the two sets, where its EDT is 0),
//   so weights == 1.0 exactly and the op is mean(BCE(inputs, targets)).
//
// R4: revert R3's fused-atomic design (agent-scope release atomics emit L2
// cache maintenance; memset graph node costs a dispatch -> net +15us).
// Two plain kernels, but k1 at 1600 blocks (~25 waves/CU) for latency hiding.

static constexpr int N_TOTAL = 32 * 320 * 320;   // 3,276,800
static constexpr int N4      = N_TOTAL / 4;      // 819,200 float4 elements
static constexpr int THREADS = 256;
static constexpr int BLOCKS  = 1600;             // 1600*256*2 == N4 exactly
static constexpr int ITERS   = 2;

__global__ __launch_bounds__(THREADS) void bce_partial_kernel(
    const float4* __restrict__ x4, const float4* __restrict__ t4,
    float* __restrict__ partial) {
    const int tid    = blockIdx.x * THREADS + threadIdx.x;
    const int stride = BLOCKS * THREADS;

    float acc = 0.0f;
    #pragma unroll
    for (int it = 0; it < ITERS; ++it) {
        const int i = tid + it * stride;
        float4 xv = x4[i];
        float4 tv = t4[i];
        float xs[4] = {xv.x, xv.y, xv.z, xv.w};
        float ts[4] = {tv.x, tv.y, tv.z, tv.w};
        #pragma unroll
        for (int j = 0; j < 4; ++j) {
            float e = __expf(-xs[j]);                       // v_exp_f32
            float p = __builtin_amdgcn_rcpf(1.0f + e);      // v_rcp_f32 (sigmoid)
            acc += -ts[j]          * __logf(p + 1e-6f)
                   - (1.0f - ts[j]) * __logf(1.0f - p + 1e-6f);
        }
    }

    // wave (64-lane) shuffle reduction
    #pragma unroll
    for (int off = 32; off > 0; off >>= 1)
        acc += __shfl_down(acc, off, 64);
    __shared__ float sdata[THREADS / 64];
    const int lane = threadIdx.x & 63;
    const int wave = threadIdx.x >> 6;
    if (lane == 0) sdata[wave] = acc;
    __syncthreads();
    if (threadIdx.x == 0) {
        float s = 0.0f;
        #pragma unroll
        for (int w = 0; w < THREADS / 64; ++w) s += sdata[w];
        partial[blockIdx.x] = s;
    }
}

static constexpr int THREADS2 = 1024;

__global__ __launch_bounds__(THREADS2) void final_reduce_kernel(
    const float* __restrict__ partial, float* __restrict__ out) {
    float acc = 0.0f;
    for (int i = threadIdx.x; i < BLOCKS; i += THREADS2) acc += partial[i];
    #pragma unroll
    for (int off = 32; off > 0; off >>= 1)
        acc += __shfl_down(acc, off, 64);
    __shared__ float sdata[THREADS2 / 64];
    const int lane = threadIdx.x & 63;
    const int wave = threadIdx.x >> 6;
    if (lane == 0) sdata[wave] = acc;
    __syncthreads();
    if (threadIdx.x == 0) {
        float s = 0.0f;
        #pragma unroll
        for (int w = 0; w < THREADS2 / 64; ++w) s += sdata[w];
        out[0] = s / (float)N_TOTAL;
    }
}

extern "C" void kernel_launch(void* const* d_in, const int* in_sizes, int n_in,
                              void* d_out, int out_size, void* d_ws, size_t ws_size,
                              hipStream_t stream) {
    const float4* x4 = (const float4*)d_in[0];   // inputs  [32,1,320,320] f32
    const float4* t4 = (const float4*)d_in[1];   // targets [32,1,320,320] f32
    float* partial   = (float*)d_ws;             // BLOCKS floats of scratch
    float* out       = (float*)d_out;            // scalar f32

    bce_partial_kernel<<<BLOCKS, THREADS, 0, stream>>>(x4, t4, partial);
    final_reduce_kernel<<<1, THREADS2, 0, stream>>>(partial, out);
}